// Round 2
// baseline (104.165 us; speedup 1.0000x reference)
//
#include <hip/hip_runtime.h>

#define TPB 512
#define NW  (TPB / 64)        // 8 waves per block
#define MAXP 4096             // largest point count per row (part 0)

// Fused StandardPershomReadout: 3 rational-hat reductions, one block per
// (part, batch-row). Each output element is written by exactly ONE block ->
// no atomics, no output pre-zeroing, single dispatch.
//
// f(d) = 1/(1+d) - 1/(1+|R-d|) == (|R-d| - d) / ((1+d)*(1+|R-d|))
// common-denominator form: 1 rcp (quarter-rate trans) instead of 2.
__global__ __launch_bounds__(TPB) void pershom_kernel(
    const float* __restrict__ h0,  const float* __restrict__ m0,
    const float* __restrict__ h0e, const float* __restrict__ m0e,
    const float* __restrict__ h1e, const float* __restrict__ m1e,
    const float* __restrict__ c0,  const float* __restrict__ r0,
    const float* __restrict__ c0e, const float* __restrict__ r0e,
    const float* __restrict__ c1e, const float* __restrict__ r1e,
    float* __restrict__ out)
{
    __shared__ float4 pts[MAXP];        // (x, y, mask, pad) — 64 KB
    __shared__ float  partial[NW][64];

    const int bid = blockIdx.x;
    const int tid = threadIdx.x;
    const int k   = tid & 63;   // center index owned by this thread
    const int sub = tid >> 6;   // wave id

    const float* h; const float* m; const float* cen; const float* rad;
    int outoff, P, D;
    if (bid < 128) {                    // part 0: D=2, P=4096
        int b = bid;
        h = h0 + (size_t)b * 4096 * 2; m = m0 + b * 4096;
        cen = c0; rad = r0; outoff = b * 192; P = 4096; D = 2;
    } else if (bid < 256) {             // part 1: D=1, P=1024
        int b = bid - 128;
        h = h0e + b * 1024; m = m0e + b * 1024;
        cen = c0e; rad = r0e; outoff = b * 192 + 64; P = 1024; D = 1;
    } else {                            // part 2: D=1, P=1024
        int b = bid - 256;
        h = h1e + b * 1024; m = m1e + b * 1024;
        cen = c1e; rad = r1e; outoff = b * 192 + 128; P = 1024; D = 1;
    }

    // Stage the whole row (x, y, mask) into LDS, coalesced.
    if (D == 2) {
        const float2* src = (const float2*)h;
        for (int i = tid; i < P; i += TPB) {
            float2 xy = src[i];
            pts[i] = make_float4(xy.x, xy.y, m[i], 0.f);
        }
    } else {
        for (int i = tid; i < P; i += TPB) {
            pts[i] = make_float4(h[i], 0.f, m[i], 0.f);
        }
    }

    // Per-thread center (registers) + radius.
    float cx, cy;
    if (D == 2) { cx = cen[2 * k]; cy = cen[2 * k + 1]; }
    else        { cx = cen[k];     cy = 0.f; }
    const float R = fabsf(rad[0]);

    __syncthreads();

    // Each wave (uniform sub) sweeps its P/NW strip; every lane reads the
    // SAME LDS address per iteration -> broadcast, conflict-free.
    // Inner math phrased so fabsf folds into input-abs modifiers:
    //   d  = |dx| + |dy|          (v_add_f32 with abs mods)
    //   t  = R - d
    //   num= |t| - d              (v_sub_f32 with abs mod)
    //   e2 = 1 + |t|              (v_add_f32 with abs mod)
    float acc = 0.f;
    const int chunk  = P / NW;
    const int pstart = sub * chunk;
    #pragma unroll 4
    for (int i = 0; i < chunk; ++i) {
        float4 pt = pts[pstart + i];
        float dx  = pt.x - cx;
        float dy  = pt.y - cy;
        float d   = fabsf(dx) + fabsf(dy);
        float t   = R - d;
        float num = fabsf(t) - d;
        float den = (1.f + d) * (1.f + fabsf(t));
        acc += (pt.z * num) * __builtin_amdgcn_rcpf(den);
    }

    partial[sub][k] = acc;
    __syncthreads();
    if (tid < 64) {
        float s = 0.f;
        #pragma unroll
        for (int w = 0; w < NW; ++w) s += partial[w][tid];
        out[outoff + tid] = s;      // sole writer of this element
    }
}

extern "C" void kernel_launch(void* const* d_in, const int* in_sizes, int n_in,
                              void* d_out, int out_size, void* d_ws, size_t ws_size,
                              hipStream_t stream) {
    const float* h0  = (const float*)d_in[0];
    const float* m0  = (const float*)d_in[1];
    const float* h0e = (const float*)d_in[2];
    const float* m0e = (const float*)d_in[3];
    const float* h1e = (const float*)d_in[4];
    const float* m1e = (const float*)d_in[5];
    const float* c0  = (const float*)d_in[6];
    const float* r0  = (const float*)d_in[7];
    const float* c0e = (const float*)d_in[8];
    const float* r0e = (const float*)d_in[9];
    const float* c1e = (const float*)d_in[10];
    const float* r1e = (const float*)d_in[11];
    float* out = (float*)d_out;

    dim3 grid(128 + 128 + 128);   // one block per (part, batch-row)
    dim3 block(TPB);
    pershom_kernel<<<grid, block, 0, stream>>>(
        h0, m0, h0e, m0e, h1e, m1e, c0, r0, c0e, r0e, c1e, r1e, out);
}

// Round 3
// 93.448 us; speedup vs baseline: 1.1147x; 1.1147x over previous
//
#include <hip/hip_runtime.h>

#define TPB 256
#define NW  (TPB / 64)          // 4 waves per block
#define PPB 1024                // points per block (uniform across all blocks)
#define PPW (PPB / NW)          // 256 points per wave
#define PAIRS_PER_WAVE (PPW / 2)

typedef float v2f __attribute__((ext_vector_type(2)));

// |v| as max(v,-v): on gfx950 this is a single v_pk_max_f32 with neg modifier
// on src1 (VOP3P has neg bits but no abs bits, so max(v,-v) beats and-mask).
static __device__ __forceinline__ v2f vabs2(v2f v) {
    return __builtin_elementwise_max(v, -v);
}

// Fused StandardPershomReadout: 3 rational-hat reductions.
// f(d) = 1/(1+d) - 1/(1+|R-d|) == (|R-d| - d) / ((1+d)*(1+|R-d|))
// (common denominator: 1 quarter-rate rcp instead of 2)
//
// Decomposition: 768 blocks x 1024 points (perfectly uniform work, 3
// blocks/CU): part0 = 128 rows x 4 slices (D=2), part1/2 = 128 rows (D=1).
// lane = center k, wave sweeps its 256-point strip reading broadcast pairs
// from LDS; packed v2f math does 2 points per iteration.
// Epilogue: 4-way LDS reduce + one atomicAdd per (block, k) into zeroed out.
__global__ __launch_bounds__(TPB) void pershom_kernel(
    const float* __restrict__ h0,  const float* __restrict__ m0,
    const float* __restrict__ h0e, const float* __restrict__ m0e,
    const float* __restrict__ h1e, const float* __restrict__ m1e,
    const float* __restrict__ c0,  const float* __restrict__ r0,
    const float* __restrict__ c0e, const float* __restrict__ r0e,
    const float* __restrict__ c1e, const float* __restrict__ r1e,
    float* __restrict__ out)
{
    // paired-AoS: pxy[j] = (x[2j], x[2j+1], y[2j], y[2j+1]); pm[j] = masks.
    // One ds_read_b128 + one ds_read_b64 (broadcast) per 2 points.
    __shared__ float4 pxy[PPB / 2];       // 8 KB
    __shared__ v2f    pm [PPB / 2];       // 4 KB
    __shared__ float  partial[NW][64];    // 1 KB

    const int bid = blockIdx.x;
    const int tid = threadIdx.x;
    const int k   = tid & 63;   // center index owned by this thread
    const int sub = tid >> 6;   // wave id

    const float* h; const float* m; const float* cen; const float* rad;
    int outidx, D;
    if (bid < 512) {                        // part 0: D=2, 4 slices per row
        int b = bid >> 2, p0 = (bid & 3) * PPB;
        h = h0 + (size_t)(b * 4096 + p0) * 2; m = m0 + b * 4096 + p0;
        cen = c0; rad = r0; outidx = b * 192 + k; D = 2;
    } else if (bid < 640) {                 // part 1: D=1, one block per row
        int b = bid - 512;
        h = h0e + b * 1024; m = m0e + b * 1024;
        cen = c0e; rad = r0e; outidx = b * 192 + 64 + k; D = 1;
    } else {                                // part 2: D=1
        int b = bid - 640;
        h = h1e + b * 1024; m = m1e + b * 1024;
        cen = c1e; rad = r1e; outidx = b * 192 + 128 + k; D = 1;
    }

    // Stage 1024 points as pairs into LDS (coalesced 16B/8B global loads).
    if (D == 2) {
        const float4* src = (const float4*)h;       // (x0,y0,x1,y1) per pair
        const v2f*    msk = (const v2f*)m;
        for (int j = tid; j < PPB / 2; j += TPB) {
            float4 q = src[j];
            pxy[j] = make_float4(q.x, q.z, q.y, q.w);  // (x0,x1,y0,y1)
            pm[j]  = msk[j];
        }
    } else {
        const v2f* src = (const v2f*)h;
        const v2f* msk = (const v2f*)m;
        for (int j = tid; j < PPB / 2; j += TPB) {
            v2f x = src[j];
            pxy[j] = make_float4(x.x, x.y, 0.f, 0.f);  // (x0,x1,-,-)
            pm[j]  = msk[j];
        }
    }

    // Per-thread center (registers) + radius.
    float cx, cy;
    if (D == 2) { cx = cen[2 * k]; cy = cen[2 * k + 1]; }
    else        { cx = cen[k];     cy = 0.f; }
    const float R = fabsf(rad[0]);

    __syncthreads();

    const v2f cx2 = {cx, cx}, cy2 = {cy, cy};
    const v2f one2 = {1.f, 1.f}, R2v = {R, R};
    v2f acc0 = {0.f, 0.f}, acc1 = {0.f, 0.f};
    const int base = sub * PAIRS_PER_WAVE;   // wave-uniform -> LDS broadcast

    if (D == 2) {
        #pragma unroll 4
        for (int j = 0; j < PAIRS_PER_WAVE; ++j) {
            float4 q = pxy[base + j];
            v2f mm = pm[base + j];
            v2f x01 = {q.x, q.y};
            v2f y01 = {q.z, q.w};
            v2f d   = vabs2(x01 - cx2) + vabs2(y01 - cy2);
            v2f at  = vabs2(R2v - d);
            v2f num = at - d;
            v2f den = (one2 + d) * (one2 + at);
            v2f rc; rc.x = __builtin_amdgcn_rcpf(den.x);
                    rc.y = __builtin_amdgcn_rcpf(den.y);
            v2f c = (mm * num) * rc;
            if (j & 1) acc1 += c; else acc0 += c;
        }
    } else {
        #pragma unroll 4
        for (int j = 0; j < PAIRS_PER_WAVE; ++j) {
            float4 q = pxy[base + j];
            v2f mm = pm[base + j];
            v2f x01 = {q.x, q.y};
            v2f d   = vabs2(x01 - cx2);
            v2f at  = vabs2(R2v - d);
            v2f num = at - d;
            v2f den = (one2 + d) * (one2 + at);
            v2f rc; rc.x = __builtin_amdgcn_rcpf(den.x);
                    rc.y = __builtin_amdgcn_rcpf(den.y);
            v2f c = (mm * num) * rc;
            if (j & 1) acc1 += c; else acc0 += c;
        }
    }

    v2f accv = acc0 + acc1;
    partial[sub][k] = accv.x + accv.y;
    __syncthreads();
    if (tid < 64) {
        float s = 0.f;
        #pragma unroll
        for (int w = 0; w < NW; ++w) s += partial[w][tid];
        atomicAdd(&out[outidx], s);   // outidx already includes +k (k==tid)
    }
}

extern "C" void kernel_launch(void* const* d_in, const int* in_sizes, int n_in,
                              void* d_out, int out_size, void* d_ws, size_t ws_size,
                              hipStream_t stream) {
    const float* h0  = (const float*)d_in[0];
    const float* m0  = (const float*)d_in[1];
    const float* h0e = (const float*)d_in[2];
    const float* m0e = (const float*)d_in[3];
    const float* h1e = (const float*)d_in[4];
    const float* m1e = (const float*)d_in[5];
    const float* c0  = (const float*)d_in[6];
    const float* r0  = (const float*)d_in[7];
    const float* c0e = (const float*)d_in[8];
    const float* r0e = (const float*)d_in[9];
    const float* c1e = (const float*)d_in[10];
    const float* r1e = (const float*)d_in[11];
    float* out = (float*)d_out;

    // out is poisoned (0xAA) before every launch; atomics need zeroed base.
    hipMemsetAsync(out, 0, (size_t)out_size * sizeof(float), stream);

    dim3 grid(512 + 128 + 128);   // uniform 1024-point blocks, 3 per CU
    dim3 block(TPB);
    pershom_kernel<<<grid, block, 0, stream>>>(
        h0, m0, h0e, m0e, h1e, m1e, c0, r0, c0e, r0e, c1e, r1e, out);
}